// Round 21
// baseline (102.288 us; speedup 1.0000x reference)
//
#include <hip/hip_runtime.h>

// SS2D: B=32,H=32,W=32,DM=128, DIN=64, N=16, R=8, L=1024
// Layouts: xc,u,delta,y = (b,d,l); z = (b,l,d); Bs,Cs = (b,n,l); out = (b,l,dm)
// r16 structure + k4 v5: phase C reduced to a 16-wide GEMV (no exp, no loads).

// ---------------- K1: xz = x @ w_in^T ; split into xc (NCHW) and z (b,l,d) ----
__global__ __launch_bounds__(256) void k1_gemm_in(
    const float* __restrict__ x, const float* __restrict__ w_in,
    float* __restrict__ xc, float* __restrict__ z)
{
    __shared__ float As[32 * 68];    // [k][m], stride 68
    __shared__ float Ws[32 * 132];   // [k][e], stride 132
    const int t  = threadIdx.x;
    const int p0 = blockIdx.x * 64;
    const int tx = t & 15, ty = t >> 4;

    float acc[4][8];
#pragma unroll
    for (int i = 0; i < 4; ++i)
#pragma unroll
        for (int j = 0; j < 8; ++j) acc[i][j] = 0.f;

    for (int kk = 0; kk < 128; kk += 32) {
        {
            const int m  = t >> 3;
            const int c4 = (t & 7) * 4;
            const float4 v0 = *reinterpret_cast<const float4*>(&x[(size_t)(p0 + m) * 128 + kk + c4]);
            const float4 v1 = *reinterpret_cast<const float4*>(&x[(size_t)(p0 + m + 32) * 128 + kk + c4]);
            As[(c4 + 0) * 68 + m] = v0.x; As[(c4 + 1) * 68 + m] = v0.y;
            As[(c4 + 2) * 68 + m] = v0.z; As[(c4 + 3) * 68 + m] = v0.w;
            As[(c4 + 0) * 68 + m + 32] = v1.x; As[(c4 + 1) * 68 + m + 32] = v1.y;
            As[(c4 + 2) * 68 + m + 32] = v1.z; As[(c4 + 3) * 68 + m + 32] = v1.w;
        }
        for (int i = t; i < 4096; i += 256) {
            const int c = i & 31, e = i >> 5;
            Ws[c * 132 + e] = w_in[(size_t)e * 128 + kk + c];
        }
        __syncthreads();
#pragma unroll
        for (int k = 0; k < 32; ++k) {
            const float4 a  = *reinterpret_cast<const float4*>(&As[k * 68 + (ty << 2)]);
            const float4 b0 = *reinterpret_cast<const float4*>(&Ws[k * 132 + (tx << 3)]);
            const float4 b1 = *reinterpret_cast<const float4*>(&Ws[k * 132 + (tx << 3) + 4]);
            const float am[4] = {a.x, a.y, a.z, a.w};
            const float bm[8] = {b0.x, b0.y, b0.z, b0.w, b1.x, b1.y, b1.z, b1.w};
#pragma unroll
            for (int i = 0; i < 4; ++i)
#pragma unroll
                for (int j = 0; j < 8; ++j)
                    acc[i][j] = fmaf(am[i], bm[j], acc[i][j]);
        }
        __syncthreads();
    }

    const int b  = p0 >> 10;
    const int l0 = (p0 & 1023) + (ty << 2);
    if (tx < 8) {
#pragma unroll
        for (int j = 0; j < 8; ++j) {
            const int e = (tx << 3) + j;
            *reinterpret_cast<float4*>(&xc[((size_t)b * 64 + e) * 1024 + l0]) =
                make_float4(acc[0][j], acc[1][j], acc[2][j], acc[3][j]);
        }
    } else {
        const int d0 = (tx - 8) << 3;
#pragma unroll
        for (int i = 0; i < 4; ++i) {
            const size_t p = (size_t)p0 + (ty << 2) + i;
            *reinterpret_cast<float4*>(&z[p * 64 + d0]) =
                make_float4(acc[i][0], acc[i][1], acc[i][2], acc[i][3]);
            *reinterpret_cast<float4*>(&z[p * 64 + d0 + 4]) =
                make_float4(acc[i][4], acc[i][5], acc[i][6], acc[i][7]);
        }
    }
}

// ---------------- K2: depthwise 3x3 conv + bias + SiLU -> u (b,d,l) ----------
__global__ __launch_bounds__(256) void k2_conv(
    const float* __restrict__ xc, const float* __restrict__ cw,
    const float* __restrict__ cb, float* __restrict__ u)
{
    __shared__ float pl[1024];
    const int bd = blockIdx.x;
    const int t  = threadIdx.x;
    const int d  = bd & 63;
    reinterpret_cast<float4*>(pl)[t] =
        reinterpret_cast<const float4*>(xc + (size_t)bd * 1024)[t];
    float w[9];
#pragma unroll
    for (int i = 0; i < 9; ++i) w[i] = cw[d * 9 + i];
    const float bias = cb[d];
    __syncthreads();
    float o[4];
#pragma unroll
    for (int i = 0; i < 4; ++i) {
        const int p  = t * 4 + i;
        const int py = p >> 5, px = p & 31;
        float s = 0.f;
#pragma unroll
        for (int ky = 0; ky < 3; ++ky) {
            const int iy = py + ky - 1;
            if (iy < 0 || iy > 31) continue;
#pragma unroll
            for (int kx = 0; kx < 3; ++kx) {
                const int ix = px + kx - 1;
                if (ix < 0 || ix > 31) continue;
                s = fmaf(pl[iy * 32 + ix], w[ky * 3 + kx], s);
            }
        }
        s += bias;
        o[i] = s / (1.f + __expf(-s));
    }
    reinterpret_cast<float4*>(u + (size_t)bd * 1024)[t] = make_float4(o[0], o[1], o[2], o[3]);
}

// ---------------- K3: x-proj (40 ch) + dt-proj + softplus --------------------
// 1024 blocks, one per 32-pixel strip. LDS-staged u tile + weights.
__global__ __launch_bounds__(256) void k3_xproj(
    const float* __restrict__ u, const float* __restrict__ xpw,
    const float* __restrict__ dtw_g, const float* __restrict__ dtb,
    float* __restrict__ delta, float* __restrict__ Bsp, float* __restrict__ Csp)
{
    __shared__ float ut[64][33];   // [d][pix]
    __shared__ float xd[40][33];   // [ch][pix]
    __shared__ float xw[64 * 40];  // [d][ch] transposed weights
    __shared__ float dwv[512];     // [d][r]
    const int t   = threadIdx.x;
    const int blk = blockIdx.x;          // 1024
    const int b   = blk >> 5;
    const int l0  = (blk & 31) * 32;

    for (int i = t; i < 2560; i += 256) {
        const int dd = i / 40, c = i - dd * 40;
        xw[i] = xpw[(size_t)c * 64 + dd];
    }
    for (int i = t; i < 512; i += 256) dwv[i] = dtw_g[i];

    {
        const int dd = t >> 2;           // 0..63
        const int lq = (t & 3) * 8;      // 0,8,16,24
        const float* up = u + ((size_t)b * 64 + dd) * 1024 + l0 + lq;
        const float4 v0 = *reinterpret_cast<const float4*>(up);
        const float4 v1 = *reinterpret_cast<const float4*>(up + 4);
        ut[dd][lq + 0] = v0.x; ut[dd][lq + 1] = v0.y;
        ut[dd][lq + 2] = v0.z; ut[dd][lq + 3] = v0.w;
        ut[dd][lq + 4] = v1.x; ut[dd][lq + 5] = v1.y;
        ut[dd][lq + 6] = v1.z; ut[dd][lq + 7] = v1.w;
    }
    __syncthreads();

    {
        const int pix = t & 31, cg = t >> 5;
        const int c0 = cg * 5;
        float a0 = 0.f, a1 = 0.f, a2 = 0.f, a3 = 0.f, a4 = 0.f;
#pragma unroll 8
        for (int dd = 0; dd < 64; ++dd) {
            const float uv = ut[dd][pix];
            const float* row = &xw[dd * 40 + c0];
            a0 = fmaf(uv, row[0], a0);
            a1 = fmaf(uv, row[1], a1);
            a2 = fmaf(uv, row[2], a2);
            a3 = fmaf(uv, row[3], a3);
            a4 = fmaf(uv, row[4], a4);
        }
        xd[c0 + 0][pix] = a0; xd[c0 + 1][pix] = a1; xd[c0 + 2][pix] = a2;
        xd[c0 + 3][pix] = a3; xd[c0 + 4][pix] = a4;
    }
    __syncthreads();

    // Bs/Cs stores: thread = (pix, nn = t>>5 in [0,8))
    {
        const int pix = t & 31, nn = t >> 5;
        float* bp = Bsp + (size_t)b * 16384 + l0 + pix;
        float* cp = Csp + (size_t)b * 16384 + l0 + pix;
        bp[(size_t)nn * 1024]       = xd[8 + nn][pix];
        bp[(size_t)(nn + 8) * 1024] = xd[16 + nn][pix];
        cp[(size_t)nn * 1024]       = xd[24 + nn][pix];
        cp[(size_t)(nn + 8) * 1024] = xd[32 + nn][pix];
    }
    // delta: thread = (pix, d-block of 8)
    {
        const int pix = t & 31;
        const int d0  = (t >> 5) * 8;
        float dts[8];
#pragma unroll
        for (int r = 0; r < 8; ++r) dts[r] = xd[r][pix];
        float* dp = delta + (size_t)b * 65536 + l0 + pix;
#pragma unroll
        for (int k = 0; k < 8; ++k) {
            const int dd = d0 + k;
            const float* r8 = &dwv[dd * 8];
            float s = dtb[dd];
            s = fmaf(dts[0], r8[0], s); s = fmaf(dts[1], r8[1], s);
            s = fmaf(dts[2], r8[2], s); s = fmaf(dts[3], r8[3], s);
            s = fmaf(dts[4], r8[4], s); s = fmaf(dts[5], r8[5], s);
            s = fmaf(dts[6], r8[6], s); s = fmaf(dts[7], r8[7], s);
            const float sp = fmaxf(s, 0.f) + log1pf(__expf(-fabsf(s)));
            dp[(size_t)dd * 1024] = sp;
        }
    }
}

// ---------------- K4 v5: scan with algebraic phase-C elimination -------------
// Phase A folds C into per-thread weights: w[4n+j] = C_{j,n} * prefix_p_{j,n},
// s1_j = sum_n C_{j,n} * q_{j,n}. Phase C is then y_j = D*u_j + s1_j +
// sum_n w[4n+j] * h_in[n] — 16 LDS reads + 64 FMAs, no exp, no global loads.
__global__ __launch_bounds__(256) void k4_scan(
    const float* __restrict__ delta, const float* __restrict__ u,
    const float* __restrict__ Bsp, const float* __restrict__ Csp,
    const float* __restrict__ A_logs, const float* __restrict__ Ds,
    float* __restrict__ y)
{
    __shared__ float Ps[256][17];
    __shared__ float qs[256][17];
    __shared__ float Sp[16][17];
    __shared__ float Sq[16][17];
    const int t = threadIdx.x;
    const int pair = blockIdx.x;    // b*64 + d
    const int b = pair >> 6, d = pair & 63;

    const float4 d4 = *reinterpret_cast<const float4*>(delta + (size_t)pair * 1024 + t * 4);
    const float4 u4 = *reinterpret_cast<const float4*>(u     + (size_t)pair * 1024 + t * 4);
    const float du0 = d4.x * u4.x, du1 = d4.y * u4.y;
    const float du2 = d4.z * u4.z, du3 = d4.w * u4.w;

    const float* Bb = Bsp + (size_t)b * 16384 + t * 4;
    const float* Cb = Csp + (size_t)b * 16384 + t * 4;

    // ---- phase A: affine reduce + fold C into (w, s1) ----
    float w[64];
    float s10 = 0.f, s11 = 0.f, s12 = 0.f, s13 = 0.f;
#pragma unroll
    for (int grp = 0; grp < 4; ++grp) {
        float4 Bv[4], Cv[4];
#pragma unroll
        for (int k = 0; k < 4; ++k) {
            Bv[k] = *reinterpret_cast<const float4*>(Bb + (size_t)(grp * 4 + k) * 1024);
            Cv[k] = *reinterpret_cast<const float4*>(Cb + (size_t)(grp * 4 + k) * 1024);
        }
#pragma unroll
        for (int k = 0; k < 4; ++k) {
            const int n = grp * 4 + k;
            const float Aval = -__expf(A_logs[d * 16 + n]);
            const float a0 = __expf(d4.x * Aval);
            const float a1 = __expf(d4.y * Aval);
            const float a2 = __expf(d4.z * Aval);
            const float a3 = __expf(d4.w * Aval);
            const float p0 = a0, p1 = p0 * a1, p2 = p1 * a2, p3 = p2 * a3;
            const float q0 = du0 * Bv[k].x;
            const float q1 = fmaf(a1, q0, du1 * Bv[k].y);
            const float q2 = fmaf(a2, q1, du2 * Bv[k].z);
            const float q3 = fmaf(a3, q2, du3 * Bv[k].w);
            w[4 * n + 0] = Cv[k].x * p0;
            w[4 * n + 1] = Cv[k].y * p1;
            w[4 * n + 2] = Cv[k].z * p2;
            w[4 * n + 3] = Cv[k].w * p3;
            s10 = fmaf(Cv[k].x, q0, s10);
            s11 = fmaf(Cv[k].y, q1, s11);
            s12 = fmaf(Cv[k].z, q2, s12);
            s13 = fmaf(Cv[k].w, q3, s13);
            Ps[t][n] = p3; qs[t][n] = q3;
        }
    }
    __syncthreads();

    // ---- phase B: scan over 256 chunks (16 segments x 16 chunks) ----
    const int n = t >> 4, g = t & 15;
    float rp[16], rq[16];
    {
        float Pseg = 1.f, qseg = 0.f;
#pragma unroll
        for (int i = 0; i < 16; ++i) {
            const int c = g * 16 + i;
            rp[i] = Ps[c][n]; rq[i] = qs[c][n];
            qseg = fmaf(rp[i], qseg, rq[i]);
            Pseg *= rp[i];
        }
        Sp[g][n] = Pseg; Sq[g][n] = qseg;
    }
    __syncthreads();
    if (t < 16) {
        float h = 0.f;
#pragma unroll
        for (int s = 0; s < 16; ++s) {
            const float Pv = Sp[s][t], qv = Sq[s][t];
            Sp[s][t] = h;
            h = fmaf(Pv, h, qv);
        }
    }
    __syncthreads();
    {
        float h = Sp[g][n];
#pragma unroll
        for (int i = 0; i < 16; ++i) {
            const int c = g * 16 + i;
            qs[c][n] = h;
            h = fmaf(rp[i], h, rq[i]);
        }
    }
    __syncthreads();

    // ---- phase C: y_j = D*u_j + s1_j + sum_n w[4n+j]*h_in[n] ----
    const float Dval = Ds[d];
    float y0 = fmaf(Dval, u4.x, s10);
    float y1 = fmaf(Dval, u4.y, s11);
    float y2 = fmaf(Dval, u4.z, s12);
    float y3 = fmaf(Dval, u4.w, s13);
#pragma unroll
    for (int nn = 0; nn < 16; ++nn) {
        const float hn = qs[t][nn];
        y0 = fmaf(w[4 * nn + 0], hn, y0);
        y1 = fmaf(w[4 * nn + 1], hn, y1);
        y2 = fmaf(w[4 * nn + 2], hn, y2);
        y3 = fmaf(w[4 * nn + 3], hn, y3);
    }
    *reinterpret_cast<float4*>(y + (size_t)pair * 1024 + t * 4) =
        make_float4(y0, y1, y2, y3);
}

// ---------------- K5: LayerNorm + silu(z) gate + out GEMM --------------------
__global__ __launch_bounds__(256) void k5_out(
    const float* __restrict__ y, const float* __restrict__ z,
    const float* __restrict__ ln_g, const float* __restrict__ ln_b,
    const float* __restrict__ w_out, float* __restrict__ out)
{
    __shared__ float yn[64 * 68];   // [l_local][d] stride 68
    __shared__ float wo[64 * 132];  // [d][c] pad 132
    const int t  = threadIdx.x;
    const int p0 = blockIdx.x * 64;
    const int b  = p0 >> 10, l0 = p0 & 1023;

    for (int i = t; i < 8192; i += 256) {
        const int c = i >> 6, dd = i & 63;
        wo[dd * 132 + c] = w_out[i];
    }

    {
        const int d = t >> 2;
        const float* yrow = y + ((size_t)b * 64 + d) * 1024 + l0;
#pragma unroll
        for (int k = 0; k < 4; ++k) {
            const int c4 = ((t & 3) + k * 4) * 4;
            const float4 v = *reinterpret_cast<const float4*>(&yrow[c4]);
            yn[(c4 + 0) * 68 + d] = v.x;
            yn[(c4 + 1) * 68 + d] = v.y;
            yn[(c4 + 2) * 68 + d] = v.z;
            yn[(c4 + 3) * 68 + d] = v.w;
        }
    }
    __syncthreads();

    const int lane = t & 63, wv = t >> 6;
    const float g = ln_g[lane], bbv = ln_b[lane];
#pragma unroll 1
    for (int i = 0; i < 16; ++i) {
        const int pl = wv * 16 + i;
        const size_t p = (size_t)p0 + pl;
        const float v  = yn[pl * 68 + lane];
        const float zv = z[p * 64 + lane];
        float s1 = v, s2 = v * v;
#pragma unroll
        for (int m = 1; m < 64; m <<= 1) {
            s1 += __shfl_xor(s1, m);
            s2 += __shfl_xor(s2, m);
        }
        const float mu   = s1 * (1.f / 64.f);
        const float var  = s2 * (1.f / 64.f) - mu * mu;
        const float rstd = rsqrtf(var + 1e-5f);
        const float sz   = zv / (1.f + __expf(-zv));
        yn[pl * 68 + lane] = ((v - mu) * rstd * g + bbv) * sz;
    }
    __syncthreads();

    const int tx = t & 31, ty = t >> 5;
    float acc[8][4];
#pragma unroll
    for (int i = 0; i < 8; ++i)
#pragma unroll
        for (int j = 0; j < 4; ++j) acc[i][j] = 0.f;

    for (int dd = 0; dd < 64; ++dd) {
        const float4 w4 = *reinterpret_cast<const float4*>(&wo[dd * 132 + (tx << 2)]);
#pragma unroll
        for (int i = 0; i < 8; ++i) {
            const float a = yn[(ty * 8 + i) * 68 + dd];
            acc[i][0] = fmaf(a, w4.x, acc[i][0]);
            acc[i][1] = fmaf(a, w4.y, acc[i][1]);
            acc[i][2] = fmaf(a, w4.z, acc[i][2]);
            acc[i][3] = fmaf(a, w4.w, acc[i][3]);
        }
    }
#pragma unroll
    for (int i = 0; i < 8; ++i) {
        const size_t p = (size_t)p0 + ty * 8 + i;
        *reinterpret_cast<float4*>(&out[p * 128 + (tx << 2)]) =
            make_float4(acc[i][0], acc[i][1], acc[i][2], acc[i][3]);
    }
}

extern "C" void kernel_launch(void* const* d_in, const int* in_sizes, int n_in,
                              void* d_out, int out_size, void* d_ws, size_t ws_size,
                              hipStream_t stream)
{
    const float* x        = (const float*)d_in[0];
    const float* w_in     = (const float*)d_in[1];
    const float* conv_w   = (const float*)d_in[2];
    const float* conv_b   = (const float*)d_in[3];
    const float* xproj_w  = (const float*)d_in[4];
    const float* dtproj_w = (const float*)d_in[5];
    const float* dtproj_b = (const float*)d_in[6];
    const float* A_logs   = (const float*)d_in[7];
    const float* Ds       = (const float*)d_in[8];
    const float* ln_g     = (const float*)d_in[9];
    const float* ln_b     = (const float*)d_in[10];
    const float* w_out    = (const float*)d_in[11];
    float* out = (float*)d_out;
    float* ws  = (float*)d_ws;

    const size_t M  = (size_t)2097152;  // 32*64*1024
    float* xc    = ws;                  // 8 MB
    float* z     = ws + M;              // 8 MB
    float* u     = ws + 2 * M;          // 8 MB
    float* delta = ws + 3 * M;          // 8 MB
    float* y     = ws + 4 * M;          // 8 MB  (b,d,l)
    float* Bsp   = ws + 5 * M;          // 2 MB
    float* Csp   = Bsp + 524288;        // 2 MB

    k1_gemm_in<<<512, 256, 0, stream>>>(x, w_in, xc, z);
    k2_conv<<<2048, 256, 0, stream>>>(xc, conv_w, conv_b, u);
    k3_xproj<<<1024, 256, 0, stream>>>(u, xproj_w, dtproj_w, dtproj_b, delta, Bsp, Csp);
    k4_scan<<<2048, 256, 0, stream>>>(delta, u, Bsp, Csp, A_logs, Ds, y);
    k5_out<<<512, 256, 0, stream>>>(y, z, ln_g, ln_b, w_out, out);
}

// Round 22
// 95.186 us; speedup vs baseline: 1.0746x; 1.0746x over previous
//
#include <hip/hip_runtime.h>

// SS2D: B=32,H=32,W=32,DM=128, DIN=64, N=16, R=8, L=1024
// Layouts: xc,u,delta,y = (b,d,l); z = (b,l,d); Bs,Cs = (b,n,l); out = (b,l,dm)
// Best-measured configuration (r16, 95.3 us): r11 structure + k4 B-register cache.

// ---------------- K1: xz = x @ w_in^T ; split into xc (NCHW) and z (b,l,d) ----
__global__ __launch_bounds__(256) void k1_gemm_in(
    const float* __restrict__ x, const float* __restrict__ w_in,
    float* __restrict__ xc, float* __restrict__ z)
{
    __shared__ float As[32 * 68];    // [k][m], stride 68
    __shared__ float Ws[32 * 132];   // [k][e], stride 132
    const int t  = threadIdx.x;
    const int p0 = blockIdx.x * 64;
    const int tx = t & 15, ty = t >> 4;

    float acc[4][8];
#pragma unroll
    for (int i = 0; i < 4; ++i)
#pragma unroll
        for (int j = 0; j < 8; ++j) acc[i][j] = 0.f;

    for (int kk = 0; kk < 128; kk += 32) {
        {
            const int m  = t >> 3;
            const int c4 = (t & 7) * 4;
            const float4 v0 = *reinterpret_cast<const float4*>(&x[(size_t)(p0 + m) * 128 + kk + c4]);
            const float4 v1 = *reinterpret_cast<const float4*>(&x[(size_t)(p0 + m + 32) * 128 + kk + c4]);
            As[(c4 + 0) * 68 + m] = v0.x; As[(c4 + 1) * 68 + m] = v0.y;
            As[(c4 + 2) * 68 + m] = v0.z; As[(c4 + 3) * 68 + m] = v0.w;
            As[(c4 + 0) * 68 + m + 32] = v1.x; As[(c4 + 1) * 68 + m + 32] = v1.y;
            As[(c4 + 2) * 68 + m + 32] = v1.z; As[(c4 + 3) * 68 + m + 32] = v1.w;
        }
        for (int i = t; i < 4096; i += 256) {
            const int c = i & 31, e = i >> 5;
            Ws[c * 132 + e] = w_in[(size_t)e * 128 + kk + c];
        }
        __syncthreads();
#pragma unroll
        for (int k = 0; k < 32; ++k) {
            const float4 a  = *reinterpret_cast<const float4*>(&As[k * 68 + (ty << 2)]);
            const float4 b0 = *reinterpret_cast<const float4*>(&Ws[k * 132 + (tx << 3)]);
            const float4 b1 = *reinterpret_cast<const float4*>(&Ws[k * 132 + (tx << 3) + 4]);
            const float am[4] = {a.x, a.y, a.z, a.w};
            const float bm[8] = {b0.x, b0.y, b0.z, b0.w, b1.x, b1.y, b1.z, b1.w};
#pragma unroll
            for (int i = 0; i < 4; ++i)
#pragma unroll
                for (int j = 0; j < 8; ++j)
                    acc[i][j] = fmaf(am[i], bm[j], acc[i][j]);
        }
        __syncthreads();
    }

    const int b  = p0 >> 10;
    const int l0 = (p0 & 1023) + (ty << 2);
    if (tx < 8) {
#pragma unroll
        for (int j = 0; j < 8; ++j) {
            const int e = (tx << 3) + j;
            *reinterpret_cast<float4*>(&xc[((size_t)b * 64 + e) * 1024 + l0]) =
                make_float4(acc[0][j], acc[1][j], acc[2][j], acc[3][j]);
        }
    } else {
        const int d0 = (tx - 8) << 3;
#pragma unroll
        for (int i = 0; i < 4; ++i) {
            const size_t p = (size_t)p0 + (ty << 2) + i;
            *reinterpret_cast<float4*>(&z[p * 64 + d0]) =
                make_float4(acc[i][0], acc[i][1], acc[i][2], acc[i][3]);
            *reinterpret_cast<float4*>(&z[p * 64 + d0 + 4]) =
                make_float4(acc[i][4], acc[i][5], acc[i][6], acc[i][7]);
        }
    }
}

// ---------------- K2: depthwise 3x3 conv + bias + SiLU -> u (b,d,l) ----------
__global__ __launch_bounds__(256) void k2_conv(
    const float* __restrict__ xc, const float* __restrict__ cw,
    const float* __restrict__ cb, float* __restrict__ u)
{
    __shared__ float pl[1024];
    const int bd = blockIdx.x;
    const int t  = threadIdx.x;
    const int d  = bd & 63;
    reinterpret_cast<float4*>(pl)[t] =
        reinterpret_cast<const float4*>(xc + (size_t)bd * 1024)[t];
    float w[9];
#pragma unroll
    for (int i = 0; i < 9; ++i) w[i] = cw[d * 9 + i];
    const float bias = cb[d];
    __syncthreads();
    float o[4];
#pragma unroll
    for (int i = 0; i < 4; ++i) {
        const int p  = t * 4 + i;
        const int py = p >> 5, px = p & 31;
        float s = 0.f;
#pragma unroll
        for (int ky = 0; ky < 3; ++ky) {
            const int iy = py + ky - 1;
            if (iy < 0 || iy > 31) continue;
#pragma unroll
            for (int kx = 0; kx < 3; ++kx) {
                const int ix = px + kx - 1;
                if (ix < 0 || ix > 31) continue;
                s = fmaf(pl[iy * 32 + ix], w[ky * 3 + kx], s);
            }
        }
        s += bias;
        o[i] = s / (1.f + __expf(-s));
    }
    reinterpret_cast<float4*>(u + (size_t)bd * 1024)[t] = make_float4(o[0], o[1], o[2], o[3]);
}

// ---------------- K3: x-proj (40 ch) + dt-proj + softplus --------------------
// 1024 blocks, one per 32-pixel strip. LDS-staged u tile + weights.
__global__ __launch_bounds__(256) void k3_xproj(
    const float* __restrict__ u, const float* __restrict__ xpw,
    const float* __restrict__ dtw_g, const float* __restrict__ dtb,
    float* __restrict__ delta, float* __restrict__ Bsp, float* __restrict__ Csp)
{
    __shared__ float ut[64][33];   // [d][pix]
    __shared__ float xd[40][33];   // [ch][pix]
    __shared__ float xw[64 * 40];  // [d][ch] transposed weights
    __shared__ float dwv[512];     // [d][r]
    const int t   = threadIdx.x;
    const int blk = blockIdx.x;          // 1024
    const int b   = blk >> 5;
    const int l0  = (blk & 31) * 32;

    for (int i = t; i < 2560; i += 256) {
        const int dd = i / 40, c = i - dd * 40;
        xw[i] = xpw[(size_t)c * 64 + dd];
    }
    for (int i = t; i < 512; i += 256) dwv[i] = dtw_g[i];

    {
        const int dd = t >> 2;           // 0..63
        const int lq = (t & 3) * 8;      // 0,8,16,24
        const float* up = u + ((size_t)b * 64 + dd) * 1024 + l0 + lq;
        const float4 v0 = *reinterpret_cast<const float4*>(up);
        const float4 v1 = *reinterpret_cast<const float4*>(up + 4);
        ut[dd][lq + 0] = v0.x; ut[dd][lq + 1] = v0.y;
        ut[dd][lq + 2] = v0.z; ut[dd][lq + 3] = v0.w;
        ut[dd][lq + 4] = v1.x; ut[dd][lq + 5] = v1.y;
        ut[dd][lq + 6] = v1.z; ut[dd][lq + 7] = v1.w;
    }
    __syncthreads();

    {
        const int pix = t & 31, cg = t >> 5;
        const int c0 = cg * 5;
        float a0 = 0.f, a1 = 0.f, a2 = 0.f, a3 = 0.f, a4 = 0.f;
#pragma unroll 8
        for (int dd = 0; dd < 64; ++dd) {
            const float uv = ut[dd][pix];
            const float* row = &xw[dd * 40 + c0];
            a0 = fmaf(uv, row[0], a0);
            a1 = fmaf(uv, row[1], a1);
            a2 = fmaf(uv, row[2], a2);
            a3 = fmaf(uv, row[3], a3);
            a4 = fmaf(uv, row[4], a4);
        }
        xd[c0 + 0][pix] = a0; xd[c0 + 1][pix] = a1; xd[c0 + 2][pix] = a2;
        xd[c0 + 3][pix] = a3; xd[c0 + 4][pix] = a4;
    }
    __syncthreads();

    // Bs/Cs stores: thread = (pix, nn = t>>5 in [0,8))
    {
        const int pix = t & 31, nn = t >> 5;
        float* bp = Bsp + (size_t)b * 16384 + l0 + pix;
        float* cp = Csp + (size_t)b * 16384 + l0 + pix;
        bp[(size_t)nn * 1024]       = xd[8 + nn][pix];
        bp[(size_t)(nn + 8) * 1024] = xd[16 + nn][pix];
        cp[(size_t)nn * 1024]       = xd[24 + nn][pix];
        cp[(size_t)(nn + 8) * 1024] = xd[32 + nn][pix];
    }
    // delta: thread = (pix, d-block of 8)
    {
        const int pix = t & 31;
        const int d0  = (t >> 5) * 8;
        float dts[8];
#pragma unroll
        for (int r = 0; r < 8; ++r) dts[r] = xd[r][pix];
        float* dp = delta + (size_t)b * 65536 + l0 + pix;
#pragma unroll
        for (int k = 0; k < 8; ++k) {
            const int dd = d0 + k;
            const float* r8 = &dwv[dd * 8];
            float s = dtb[dd];
            s = fmaf(dts[0], r8[0], s); s = fmaf(dts[1], r8[1], s);
            s = fmaf(dts[2], r8[2], s); s = fmaf(dts[3], r8[3], s);
            s = fmaf(dts[4], r8[4], s); s = fmaf(dts[5], r8[5], s);
            s = fmaf(dts[6], r8[6], s); s = fmaf(dts[7], r8[7], s);
            const float sp = fmaxf(s, 0.f) + log1pf(__expf(-fabsf(s)));
            dp[(size_t)dd * 1024] = sp;
        }
    }
}

// ---------------- K4: timestep-major chunked scan (block per (b,d)) ----------
// B register cache: all 16 B-float4s batch-loaded up-front and reused in
// phase C -> B read once per block, high MLP.
__global__ __launch_bounds__(256) void k4_scan(
    const float* __restrict__ delta, const float* __restrict__ u,
    const float* __restrict__ Bsp, const float* __restrict__ Csp,
    const float* __restrict__ A_logs, const float* __restrict__ Ds,
    float* __restrict__ y)
{
    __shared__ float Ps[256][17];
    __shared__ float qs[256][17];
    __shared__ float Sp[16][17];
    __shared__ float Sq[16][17];
    const int t = threadIdx.x;
    const int pair = blockIdx.x;    // b*64 + d
    const int b = pair >> 6, d = pair & 63;

    const float4 d4 = *reinterpret_cast<const float4*>(delta + (size_t)pair * 1024 + t * 4);
    const float4 u4 = *reinterpret_cast<const float4*>(u     + (size_t)pair * 1024 + t * 4);
    const float du0 = d4.x * u4.x, du1 = d4.y * u4.y;
    const float du2 = d4.z * u4.z, du3 = d4.w * u4.w;

    const float* Bb = Bsp + (size_t)b * 16384 + t * 4;
    const float* Cb = Csp + (size_t)b * 16384 + t * 4;

    // batched B load: 16 independent float4 loads -> register cache
    float Bc[64];
#pragma unroll
    for (int n = 0; n < 16; ++n)
        *reinterpret_cast<float4*>(&Bc[4 * n]) =
            *reinterpret_cast<const float4*>(Bb + (size_t)n * 1024);

    float A[16];
#pragma unroll
    for (int n = 0; n < 16; ++n) A[n] = -__expf(A_logs[d * 16 + n]);

    // ---- phase A: per-state 4-step affine reduce (no loads in loop) ----
#pragma unroll
    for (int n = 0; n < 16; ++n) {
        float a, P, q;
        a = __expf(d4.x * A[n]); P = a;   q = du0 * Bc[4*n+0];
        a = __expf(d4.y * A[n]); P *= a;  q = fmaf(a, q, du1 * Bc[4*n+1]);
        a = __expf(d4.z * A[n]); P *= a;  q = fmaf(a, q, du2 * Bc[4*n+2]);
        a = __expf(d4.w * A[n]); P *= a;  q = fmaf(a, q, du3 * Bc[4*n+3]);
        Ps[t][n] = P; qs[t][n] = q;
    }
    __syncthreads();

    // ---- phase B: scan over 256 chunks (16 segments x 16 chunks) ----
    const int n = t >> 4, g = t & 15;
    float rp[16], rq[16];
    {
        float Pseg = 1.f, qseg = 0.f;
#pragma unroll
        for (int i = 0; i < 16; ++i) {
            const int c = g * 16 + i;
            rp[i] = Ps[c][n]; rq[i] = qs[c][n];
            qseg = fmaf(rp[i], qseg, rq[i]);
            Pseg *= rp[i];
        }
        Sp[g][n] = Pseg; Sq[g][n] = qseg;
    }
    __syncthreads();
    if (t < 16) {
        float h = 0.f;
#pragma unroll
        for (int s = 0; s < 16; ++s) {
            const float Pv = Sp[s][t], qv = Sq[s][t];
            Sp[s][t] = h;
            h = fmaf(Pv, h, qv);
        }
    }
    __syncthreads();
    {
        float h = Sp[g][n];
#pragma unroll
        for (int i = 0; i < 16; ++i) {
            const int c = g * 16 + i;
            qs[c][n] = h;
            h = fmaf(rp[i], h, rq[i]);
        }
    }
    __syncthreads();

    // ---- phase C: replay with cached B; only C4 loads (independent) ----
    const float Dval = Ds[d];
    float y0 = Dval * u4.x, y1 = Dval * u4.y, y2 = Dval * u4.z, y3 = Dval * u4.w;
#pragma unroll
    for (int nn = 0; nn < 16; ++nn) {
        const float4 C4 = *reinterpret_cast<const float4*>(Cb + (size_t)nn * 1024);
        float h = qs[t][nn];
        float a;
        a = __expf(d4.x * A[nn]); h = fmaf(a, h, du0 * Bc[4*nn+0]); y0 = fmaf(h, C4.x, y0);
        a = __expf(d4.y * A[nn]); h = fmaf(a, h, du1 * Bc[4*nn+1]); y1 = fmaf(h, C4.y, y1);
        a = __expf(d4.z * A[nn]); h = fmaf(a, h, du2 * Bc[4*nn+2]); y2 = fmaf(h, C4.z, y2);
        a = __expf(d4.w * A[nn]); h = fmaf(a, h, du3 * Bc[4*nn+3]); y3 = fmaf(h, C4.w, y3);
    }
    *reinterpret_cast<float4*>(y + (size_t)pair * 1024 + t * 4) =
        make_float4(y0, y1, y2, y3);
}

// ---------------- K5: LayerNorm + silu(z) gate + out GEMM --------------------
__global__ __launch_bounds__(256) void k5_out(
    const float* __restrict__ y, const float* __restrict__ z,
    const float* __restrict__ ln_g, const float* __restrict__ ln_b,
    const float* __restrict__ w_out, float* __restrict__ out)
{
    __shared__ float yn[64 * 68];   // [l_local][d] stride 68
    __shared__ float wo[64 * 132];  // [d][c] pad 132
    const int t  = threadIdx.x;
    const int p0 = blockIdx.x * 64;
    const int b  = p0 >> 10, l0 = p0 & 1023;

    for (int i = t; i < 8192; i += 256) {
        const int c = i >> 6, dd = i & 63;
        wo[dd * 132 + c] = w_out[i];
    }

    {
        const int d = t >> 2;
        const float* yrow = y + ((size_t)b * 64 + d) * 1024 + l0;
#pragma unroll
        for (int k = 0; k < 4; ++k) {
            const int c4 = ((t & 3) + k * 4) * 4;
            const float4 v = *reinterpret_cast<const float4*>(&yrow[c4]);
            yn[(c4 + 0) * 68 + d] = v.x;
            yn[(c4 + 1) * 68 + d] = v.y;
            yn[(c4 + 2) * 68 + d] = v.z;
            yn[(c4 + 3) * 68 + d] = v.w;
        }
    }
    __syncthreads();

    const int lane = t & 63, wv = t >> 6;
    const float g = ln_g[lane], bbv = ln_b[lane];
#pragma unroll 1
    for (int i = 0; i < 16; ++i) {
        const int pl = wv * 16 + i;
        const size_t p = (size_t)p0 + pl;
        const float v  = yn[pl * 68 + lane];
        const float zv = z[p * 64 + lane];
        float s1 = v, s2 = v * v;
#pragma unroll
        for (int m = 1; m < 64; m <<= 1) {
            s1 += __shfl_xor(s1, m);
            s2 += __shfl_xor(s2, m);
        }
        const float mu   = s1 * (1.f / 64.f);
        const float var  = s2 * (1.f / 64.f) - mu * mu;
        const float rstd = rsqrtf(var + 1e-5f);
        const float sz   = zv / (1.f + __expf(-zv));
        yn[pl * 68 + lane] = ((v - mu) * rstd * g + bbv) * sz;
    }
    __syncthreads();

    const int tx = t & 31, ty = t >> 5;
    float acc[8][4];
#pragma unroll
    for (int i = 0; i < 8; ++i)
#pragma unroll
        for (int j = 0; j < 4; ++j) acc[i][j] = 0.f;

    for (int dd = 0; dd < 64; ++dd) {
        const float4 w4 = *reinterpret_cast<const float4*>(&wo[dd * 132 + (tx << 2)]);
#pragma unroll
        for (int i = 0; i < 8; ++i) {
            const float a = yn[(ty * 8 + i) * 68 + dd];
            acc[i][0] = fmaf(a, w4.x, acc[i][0]);
            acc[i][1] = fmaf(a, w4.y, acc[i][1]);
            acc[i][2] = fmaf(a, w4.z, acc[i][2]);
            acc[i][3] = fmaf(a, w4.w, acc[i][3]);
        }
    }
#pragma unroll
    for (int i = 0; i < 8; ++i) {
        const size_t p = (size_t)p0 + ty * 8 + i;
        *reinterpret_cast<float4*>(&out[p * 128 + (tx << 2)]) =
            make_float4(acc[i][0], acc[i][1], acc[i][2], acc[i][3]);
    }
}

extern "C" void kernel_launch(void* const* d_in, const int* in_sizes, int n_in,
                              void* d_out, int out_size, void* d_ws, size_t ws_size,
                              hipStream_t stream)
{
    const float* x        = (const float*)d_in[0];
    const float* w_in     = (const float*)d_in[1];
    const float* conv_w   = (const float*)d_in[2];
    const float* conv_b   = (const float*)d_in[3];
    const float* xproj_w  = (const float*)d_in[4];
    const float* dtproj_w = (const float*)d_in[5];
    const float* dtproj_b = (const float*)d_in[6];
    const float* A_logs   = (const float*)d_in[7];
    const float* Ds       = (const float*)d_in[8];
    const float* ln_g     = (const float*)d_in[9];
    const float* ln_b     = (const float*)d_in[10];
    const float* w_out    = (const float*)d_in[11];
    float* out = (float*)d_out;
    float* ws  = (float*)d_ws;

    const size_t M  = (size_t)2097152;  // 32*64*1024
    float* xc    = ws;                  // 8 MB
    float* z     = ws + M;              // 8 MB
    float* u     = ws + 2 * M;          // 8 MB
    float* delta = ws + 3 * M;          // 8 MB
    float* y     = ws + 4 * M;          // 8 MB  (b,d,l)
    float* Bsp   = ws + 5 * M;          // 2 MB
    float* Csp   = Bsp + 524288;        // 2 MB

    k1_gemm_in<<<512, 256, 0, stream>>>(x, w_in, xc, z);
    k2_conv<<<2048, 256, 0, stream>>>(xc, conv_w, conv_b, u);
    k3_xproj<<<1024, 256, 0, stream>>>(u, xproj_w, dtproj_w, dtproj_b, delta, Bsp, Csp);
    k4_scan<<<2048, 256, 0, stream>>>(delta, u, Bsp, Csp, A_logs, Ds, y);
    k5_out<<<512, 256, 0, stream>>>(y, z, ln_g, ln_b, w_out, out);
}